// Round 21
// baseline (113.609 us; speedup 1.0000x reference)
//
#include <hip/hip_runtime.h>
#include <hip/hip_bf16.h>

#define HH 512
#define WW 512
#define HWSZ (HH*WW)
#define NB 32
#define NLD 100000
#define NF 16
#define EPSV 1e-3f
#define TILE 16
#define GR (TILE+4)    // grid halo tile 20x20
#define HCELLS (GR*GR) // 400
#define RDW 10         // dwords per halo row in E/O copies
#define YR (TILE+2)    // y1/proj tile 18x18
#define NGRP 21        // ceil(324/16) pixel-groups
#define PSLOTS (NGRP*16)  // 336
#define PSTRB 10       // proj row stride in shorts (taps 0..8 + pad)
#define PBUF (PSLOTS*PSTRB)

#define NTILE 1024     // 32x32 tiles of 16x16
#define CAPT 256       // halo-bucket capacity (λ=152.6, σ=12.4)

typedef __attribute__((ext_vector_type(4))) short bf16x4;
typedef __attribute__((ext_vector_type(4))) float f32x4;

static __device__ __forceinline__ unsigned short f2bfu(float f) {
  __hip_bfloat16 h = __float2bfloat16(f);
  return __builtin_bit_cast(unsigned short, h);
}
static __device__ __forceinline__ unsigned cvtpk(float a, float b) {
  unsigned r;
  asm("v_cvt_pk_bf16_f32 %0, %1, %2" : "=v"(r) : "v"(a), "v"(b));
  return r;
}
// K=16 bf16 MFMA (lane l: m/n=l&15, k=(l>>4)*4+jj). Guard must be inside
// __HIP_DEVICE_COMPILE__ — __has_builtin(amdgcn) is FALSE on the host pass.
static __device__ __forceinline__ f32x4 mfma16(bf16x4 a, bf16x4 b, f32x4 c) {
#if defined(__HIP_DEVICE_COMPILE__)
#if __has_builtin(__builtin_amdgcn_mfma_f32_16x16x16_bf16)
  return __builtin_amdgcn_mfma_f32_16x16x16_bf16(a, b, c, 0, 0, 0);
#else
  return __builtin_amdgcn_mfma_f32_16x16x16bf16_1k(a, b, c, 0, 0, 0);
#endif
#else
  return c;  // host stub, never executed
#endif
}

// ---- bin: halo-bucket per tile (R13/R14-proven). Block 0 also builds the
// K=16 A-fragments (lane l: m=l&15, k=(l>>4)*4+jj), 9 BN-shift consts and
// their total (g_const[9], used by interior tiles). ----
__global__ __launch_bounds__(256) void bin_k(const int* __restrict__ idx,
    const float* __restrict__ w1g, const float* __restrict__ b1g,
    const float* __restrict__ w2g, const float* __restrict__ gammag,
    const float* __restrict__ betag, const float* __restrict__ mmg,
    const float* __restrict__ mvg,
    uint2* __restrict__ w1A, uint2* __restrict__ w2A, float* __restrict__ g_const,
    unsigned* __restrict__ g_tcnt, unsigned* __restrict__ g_tbkt) {
  __shared__ unsigned ht[NTILE], bt[NTILE];
  const int lid = threadIdx.x;

  if (blockIdx.x == 0 && lid < 64) {
    int m = lid & 15, kg = lid >> 4;
    bf16x4 a1, a2;
    #pragma unroll
    for (int jj = 0; jj < 4; ++jj) {
      int k = kg*4 + jj;
      float v1 = 0.f;
      if (k < 12) {
        int col = k & 3, row = k >> 2;
        if (col < 3) v1 = w1g[(row*3+col)*NF + m];
      } else if (k == 12) v1 = b1g[m];
      a1[jj] = (short)f2bfu(v1);
      float v2 = 0.f;
      if (m < 9) {
        float bnA = gammag[k]*rsqrtf(mvg[k] + EPSV);
        v2 = w2g[m*NF + k]*bnA;
      }
      a2[jj] = (short)f2bfu(v2);
    }
    w1A[lid] = __builtin_bit_cast(uint2, a1);
    w2A[lid] = __builtin_bit_cast(uint2, a2);
  }
  if (blockIdx.x == 0 && lid >= 64 && lid < 64+10) {
    int t = lid - 64;
    if (t < 9) {
      float s = 0.f;
      #pragma unroll
      for (int c = 0; c < NF; ++c) {
        float A = gammag[c]*rsqrtf(mvg[c] + EPSV);
        s += w2g[t*NF + c]*(betag[c] - mmg[c]*A);
      }
      g_const[t] = s;
    } else {
      float s = 0.f;                       // total: sum over all 9 taps
      for (int tt = 0; tt < 9; ++tt)
        #pragma unroll
        for (int c = 0; c < NF; ++c) {
          float A = gammag[c]*rsqrtf(mvg[c] + EPSV);
          s += w2g[tt*NF + c]*(betag[c] - mmg[c]*A);
        }
      g_const[9] = s;
    }
  }

  for (int q = lid; q < NTILE; q += 256) ht[q] = 0;
  __syncthreads();
  for (int i = blockIdx.x*256 + lid; i < NLD; i += 64*256) {
    int cell = idx[i];
    int h = cell >> 9, w = cell & 511;
    int thA = (h-2)>>4, thB = (h+2)>>4;
    int twA = (w-2)>>4, twB = (w+2)>>4;
    #pragma unroll
    for (int ah = 0; ah < 2; ++ah) {
      int th = ah ? thB : thA;
      if (th < 0 || th > 31 || (ah && thB == thA)) continue;
      #pragma unroll
      for (int aw = 0; aw < 2; ++aw) {
        int tw = aw ? twB : twA;
        if (tw < 0 || tw > 31 || (aw && twB == twA)) continue;
        atomicAdd(&ht[th*32 + tw], 1u);
      }
    }
  }
  __syncthreads();
  for (int q = lid; q < NTILE; q += 256) {
    bt[q] = ht[q] ? atomicAdd(&g_tcnt[q], ht[q]) : 0u;
    ht[q] = 0;
  }
  __syncthreads();
  for (int i = blockIdx.x*256 + lid; i < NLD; i += 64*256) {
    int cell = idx[i];
    int h = cell >> 9, w = cell & 511;
    int thA = (h-2)>>4, thB = (h+2)>>4;
    int twA = (w-2)>>4, twB = (w+2)>>4;
    #pragma unroll
    for (int ah = 0; ah < 2; ++ah) {
      int th = ah ? thB : thA;
      if (th < 0 || th > 31 || (ah && thB == thA)) continue;
      #pragma unroll
      for (int aw = 0; aw < 2; ++aw) {
        int tw = aw ? twB : twA;
        if (tw < 0 || tw > 31 || (aw && twB == twA)) continue;
        int t = th*32 + tw;
        unsigned pt = bt[t] + atomicAdd(&ht[t], 1u);
        unsigned pos = (unsigned)(h - th*16 + 2)*20u + (unsigned)(w - tw*16 + 2);
        if (pt < CAPT) g_tbkt[(size_t)t*CAPT + pt] = ((unsigned)i << 9) | pos;
      }
    }
  }
}

// A+P inner loop (R18-verified), templated on INTERIOR: interior tiles skip
// the per-group bounds mask entirely (val is identically true there).
template<bool INTERIOR>
static __device__ __forceinline__ void ap_loop(int l, int wid, int ty0, int tx0,
    const unsigned* gE0, const unsigned* gE1, const unsigned* gO0, const unsigned* gO1,
    unsigned short* s_projb, bf16x4 w1frag, bf16x4 w2frag) {
  const int n_px = l & 15, kg = l >> 4;
  for (int grp = wid; grp < NGRP; grp += 4) {
    int p = grp*16 + n_px;
    unsigned rr = ((unsigned)p * 3641u) >> 16;     // p/18
    unsigned cc = (unsigned)p - rr*18u;
    bool val = true;
    if (!INTERIOR) {
      int yh = ty0 - 1 + (int)rr, yw = tx0 - 1 + (int)cc;
      val = ((unsigned)yh < HH) & ((unsigned)yw < WW);
    }
    int o = (int)rr*RDW + (int)(cc >> 1) + kg*RDW;   // kg = window row
    const unsigned* g0 = (cc & 1) ? gO0 : gE0;
    const unsigned* g1 = (cc & 1) ? gO1 : gE1;

    // gfrag: kg0/1/2 = window rows rr..rr+2 (4 cells, col3 junk); kg3 = bias 1.0 @k12
    unsigned ga0, ga1, gb0, gb1;
    if (kg < 3) { ga0 = g0[o]; ga1 = g0[o+1]; gb0 = g1[o]; gb1 = g1[o+1]; }
    else        { ga0 = 0x00003F80u; ga1 = 0u; gb0 = 0x00003F80u; gb1 = 0u; }
    bf16x4 gf0 = __builtin_bit_cast(bf16x4, make_uint2(ga0, ga1));
    bf16x4 gf1 = __builtin_bit_cast(bf16x4, make_uint2(gb0, gb1));

    // conv1+bias x2 (K=16)
    f32x4 z = {0.f,0.f,0.f,0.f};
    f32x4 d10 = mfma16(w1frag, gf0, z);
    f32x4 d11 = mfma16(w1frag, gf1, z);

    // relu + pack; D layout == proj B layout (lane: px=l&15, ch 4kg..4kg+3)
    unsigned u0a = cvtpk(fmaxf(d10[0],0.f), fmaxf(d10[1],0.f));
    unsigned u0b = cvtpk(fmaxf(d10[2],0.f), fmaxf(d10[3],0.f));
    unsigned u1a = cvtpk(fmaxf(d11[0],0.f), fmaxf(d11[1],0.f));
    unsigned u1b = cvtpk(fmaxf(d11[2],0.f), fmaxf(d11[3],0.f));
    if (!INTERIOR && !val) { u0a = u0b = u1a = u1b = 0u; }   // OOB y1 -> 0
    bf16x4 bf0 = __builtin_bit_cast(bf16x4, make_uint2(u0a, u0b));
    bf16x4 bf1 = __builtin_bit_cast(bf16x4, make_uint2(u1a, u1b));

    // proj x2 (K=16): D rows = taps 4kg..4kg+3
    f32x4 d0 = mfma16(w2frag, bf0, z);
    f32x4 d1 = mfma16(w2frag, bf1, z);

    if (kg < 2) {
      *(uint2*)&s_projb[p*PSTRB + kg*4]        = make_uint2(cvtpk(d0[0],d0[1]), cvtpk(d0[2],d0[3]));
      *(uint2*)&s_projb[PBUF + p*PSTRB + kg*4] = make_uint2(cvtpk(d1[0],d1[1]), cvtpk(d1[2],d1[3]));
    } else if (kg == 2) {
      s_projb[p*PSTRB + 8]        = (unsigned short)(cvtpk(d0[0], d0[0]) & 0xFFFFu);  // tap 8
      s_projb[PBUF + p*PSTRB + 8] = (unsigned short)(cvtpk(d1[0], d1[0]) & 0xFFFFu);
    }
  }
}

// ---- conv: tile x batch-pair. K=16 dual-MFMA, conv1 output feeds proj
// directly. Interior tiles (900/1024) take a mask-free specialized path. ----
__global__ __launch_bounds__(256, 4) void conv_k(
    const uint2* __restrict__ w1Ag, const uint2* __restrict__ w2Ag,
    const float* __restrict__ g_const, const float* __restrict__ b2g,
    const float* __restrict__ x,
    const unsigned* __restrict__ g_tcnt, const unsigned* __restrict__ g_tbkt,
    float* __restrict__ out)
{
  __shared__ float s_gridf[2*HCELLS];                  // scatter acc; reused as ytile
  __shared__ unsigned s_gE[2][GR*RDW];                 // bf16-pair copies, even start
  __shared__ unsigned s_gO[2][GR*RDW];                 // odd start
  __shared__ __align__(8) unsigned short s_projb[2*PBUF];
  __shared__ float s_const[12];
  // ~19.5 KB

  const int lid = threadIdx.x;
  const int j = blockIdx.x;
  const int b0 = (j & 15) * 2;
  const int tile = j >> 4;
  const int trow = tile >> 5, tcol = tile & 31;
  const int ty0 = trow * TILE, tx0 = tcol * TILE;
  const bool interior = (trow >= 1) & (trow <= 30) & (tcol >= 1) & (tcol <= 30);

  const int l = lid & 63;
  const int wid = lid >> 6;
  const bf16x4 w1frag = __builtin_bit_cast(bf16x4, w1Ag[l]);
  const bf16x4 w2frag = __builtin_bit_cast(bf16x4, w2Ag[l]);

  if (lid < 10) s_const[lid] = g_const[lid];
  for (int q = lid; q < 2*HCELLS; q += 256) s_gridf[q] = 0.f;
  __syncthreads();

  const unsigned nT = min(g_tcnt[tile], (unsigned)CAPT);
  const unsigned* tb = g_tbkt + (size_t)tile*CAPT;
  const float* xb0 = x + (size_t)b0*NLD;
  const float* xb1 = xb0 + NLD;
  for (unsigned k2 = lid; k2 < nT; k2 += 256) {
    unsigned e = tb[k2];
    unsigned pos = e & 511, i = e >> 9;
    atomicAdd(&s_gridf[pos],          xb0[i]);
    atomicAdd(&s_gridf[HCELLS + pos], xb1[i]);
  }
  __syncthreads();

  // quantize to bf16 pair-copies: E dword jd = cells {2jd,2jd+1}; O = {2jd+1,2jd+2}
  for (int q = lid; q < 2*GR*RDW; q += 256) {
    int bb = q >= GR*RDW;
    int rj = q - bb*GR*RDW;
    int r = rj / RDW, jd = rj - r*RDW;
    const float* f = &s_gridf[bb*HCELLS + r*GR];
    int c0 = jd*2;
    s_gE[bb][rj] = cvtpk(f[c0], f[c0+1]);
    s_gO[bb][rj] = cvtpk(f[c0+1], (c0+2 < GR) ? f[c0+2] : 0.f);
  }
  __syncthreads();

  // ---- A+P: wave-uniform interior/border specialization ----
  if (interior)
    ap_loop<true >(l, wid, ty0, tx0, s_gE[0], s_gE[1], s_gO[0], s_gO[1], s_projb, w1frag, w2frag);
  else
    ap_loop<false>(l, wid, ty0, tx0, s_gE[0], s_gE[1], s_gO[0], s_gO[1], s_projb, w1frag, w2frag);
  __syncthreads();

  // ---- phase B: out = b2 + consts + sum_t proj[t] ----
  float* s_ytile = s_gridf;
  {
    const int ty = lid >> 4, tx = lid & 15;
    float base, acc0 = 0.f, acc1 = 0.f;
    if (interior) {
      base = b2g[0] + s_const[9];          // all 9 taps valid -> precomputed total
      #pragma unroll
      for (int kh = 0; kh < 3; ++kh)
        #pragma unroll
        for (int kw = 0; kw < 3; ++kw) {
          int o = ((ty+kh)*YR + tx+kw)*PSTRB + kh*3+kw;
          acc0 += __uint_as_float((unsigned)s_projb[o] << 16);
          acc1 += __uint_as_float((unsigned)s_projb[PBUF + o] << 16);
        }
    } else {
      bool vh[3], vw[3];
      #pragma unroll
      for (int kk = 0; kk < 3; ++kk) {
        vh[kk] = (unsigned)(ty0 + ty + kk - 1) < HH;
        vw[kk] = (unsigned)(tx0 + tx + kk - 1) < WW;
      }
      base = b2g[0];
      #pragma unroll
      for (int kh = 0; kh < 3; ++kh)
        #pragma unroll
        for (int kw = 0; kw < 3; ++kw) {
          if (vh[kh] & vw[kw]) base += s_const[kh*3+kw];
          int o = ((ty+kh)*YR + tx+kw)*PSTRB + kh*3+kw;
          acc0 += __uint_as_float((unsigned)s_projb[o] << 16);
          acc1 += __uint_as_float((unsigned)s_projb[PBUF + o] << 16);
        }
    }
    s_ytile[lid]       = base + acc0;
    s_ytile[256 + lid] = base + acc1;
  }
  __syncthreads();

  // ---- fused gather epilogue ----
  for (unsigned k2 = lid; k2 < nT; k2 += 256) {
    unsigned e = tb[k2];
    unsigned pos = e & 511;
    unsigned py = (pos * 3277u) >> 16;   // pos/20
    unsigned px2 = pos - py*20u;
    if (py >= 2 && py < 18 && px2 >= 2 && px2 < 18) {
      unsigned i = e >> 9;
      int o = (int)((py-2)*16 + (px2-2));
      out[(size_t)b0*NLD + i]     = xb0[i] + s_ytile[o];
      out[(size_t)(b0+1)*NLD + i] = xb1[i] + s_ytile[256 + o];
    }
  }
}

extern "C" void kernel_launch(void* const* d_in, const int* in_sizes, int n_in,
                              void* d_out, int out_size, void* d_ws, size_t ws_size,
                              hipStream_t stream) {
  const float* x     = (const float*)d_in[0];
  const float* w1    = (const float*)d_in[1];
  const float* b1    = (const float*)d_in[2];
  const float* gamma = (const float*)d_in[3];
  const float* beta  = (const float*)d_in[4];
  const float* mmean = (const float*)d_in[5];
  const float* mvar  = (const float*)d_in[6];
  const float* w2    = (const float*)d_in[7];
  const float* b2    = (const float*)d_in[8];
  const int*   idx   = (const int*)d_in[9];
  float* out = (float*)d_out;

  unsigned* g_tcnt = (unsigned*)d_ws;                     // 1024
  unsigned* g_tbkt = g_tcnt + NTILE;                      // 1 MB
  uint2*    w1A    = (uint2*)(g_tbkt + (size_t)NTILE*CAPT);
  uint2*    w2A    = w1A + 64;
  float*    gconst = (float*)(w2A + 64);                  // 10 floats

  (void)hipMemsetAsync(g_tcnt, 0, NTILE*sizeof(unsigned), stream);

  bin_k<<<dim3(64), dim3(256), 0, stream>>>(idx, w1, b1, w2, gamma, beta,
                                            mmean, mvar, w1A, w2A, gconst,
                                            g_tcnt, g_tbkt);

  conv_k<<<dim3((NB/2) * NTILE), dim3(256), 0, stream>>>(
      w1A, w2A, gconst, b2, x, g_tcnt, g_tbkt, out);
}

// Round 22
// 90.819 us; speedup vs baseline: 1.2509x; 1.2509x over previous
//
#include <hip/hip_runtime.h>
#include <hip/hip_bf16.h>

#define HH 512
#define WW 512
#define HWSZ (HH*WW)
#define NB 32
#define NLD 100000
#define NF 16
#define EPSV 1e-3f
#define TILE 16
#define GR (TILE+4)    // grid halo tile 20x20
#define HCELLS (GR*GR) // 400
#define RDW 10         // dwords per halo row in E/O copies
#define YR (TILE+2)    // y1/proj tile 18x18
#define NGRP 21        // ceil(324/16) pixel-groups
#define PSLOTS (NGRP*16)  // 336
#define PSTRB 10       // proj row stride in shorts (taps 0..8 + pad)
#define PBUF (PSLOTS*PSTRB)

#define NTILE 1024     // 32x32 tiles of 16x16
#define CAPT 256       // halo-bucket capacity (λ=152.6, σ=12.4)

typedef __attribute__((ext_vector_type(4))) short bf16x4;
typedef __attribute__((ext_vector_type(4))) float f32x4;

static __device__ __forceinline__ unsigned short f2bfu(float f) {
  __hip_bfloat16 h = __float2bfloat16(f);
  return __builtin_bit_cast(unsigned short, h);
}
static __device__ __forceinline__ unsigned cvtpk(float a, float b) {
  unsigned r;
  asm("v_cvt_pk_bf16_f32 %0, %1, %2" : "=v"(r) : "v"(a), "v"(b));
  return r;
}
// K=16 bf16 MFMA (lane l: m/n=l&15, k=(l>>4)*4+jj). Guard must be inside
// __HIP_DEVICE_COMPILE__ — __has_builtin(amdgcn) is FALSE on the host pass.
static __device__ __forceinline__ f32x4 mfma16(bf16x4 a, bf16x4 b, f32x4 c) {
#if defined(__HIP_DEVICE_COMPILE__)
#if __has_builtin(__builtin_amdgcn_mfma_f32_16x16x16_bf16)
  return __builtin_amdgcn_mfma_f32_16x16x16_bf16(a, b, c, 0, 0, 0);
#else
  return __builtin_amdgcn_mfma_f32_16x16x16bf16_1k(a, b, c, 0, 0, 0);
#endif
#else
  return c;  // host stub, never executed
#endif
}

// ---- bin: halo-bucket per tile (R13/R14-proven). Block 0 also builds the
// K=16 A-fragments (lane l: m=l&15, k=(l>>4)*4+jj) and 9 BN-shift consts.
// conv1 A: k=4*row+col (rows 0..2 of the 3x3 window read as 4-cell row
// dwords; col==3 junk -> 0); k12 = b1 (bias, B supplies 1.0); k13..15 = 0.
// proj A: m=tap(<9), k=ch, w2' = w2*bnA (BN scale folded). ----
__global__ __launch_bounds__(256) void bin_k(const int* __restrict__ idx,
    const float* __restrict__ w1g, const float* __restrict__ b1g,
    const float* __restrict__ w2g, const float* __restrict__ gammag,
    const float* __restrict__ betag, const float* __restrict__ mmg,
    const float* __restrict__ mvg,
    uint2* __restrict__ w1A, uint2* __restrict__ w2A, float* __restrict__ g_const,
    unsigned* __restrict__ g_tcnt, unsigned* __restrict__ g_tbkt) {
  __shared__ unsigned ht[NTILE], bt[NTILE];
  const int lid = threadIdx.x;

  if (blockIdx.x == 0 && lid < 64) {
    int m = lid & 15, kg = lid >> 4;
    bf16x4 a1, a2;
    #pragma unroll
    for (int jj = 0; jj < 4; ++jj) {
      int k = kg*4 + jj;
      float v1 = 0.f;
      if (k < 12) {
        int col = k & 3, row = k >> 2;
        if (col < 3) v1 = w1g[(row*3+col)*NF + m];
      } else if (k == 12) v1 = b1g[m];
      a1[jj] = (short)f2bfu(v1);
      float v2 = 0.f;
      if (m < 9) {
        float bnA = gammag[k]*rsqrtf(mvg[k] + EPSV);
        v2 = w2g[m*NF + k]*bnA;
      }
      a2[jj] = (short)f2bfu(v2);
    }
    w1A[lid] = __builtin_bit_cast(uint2, a1);
    w2A[lid] = __builtin_bit_cast(uint2, a2);
  }
  if (blockIdx.x == 0 && lid >= 64 && lid < 64+9) {
    int t = lid - 64;
    float s = 0.f;
    #pragma unroll
    for (int c = 0; c < NF; ++c) {
      float A = gammag[c]*rsqrtf(mvg[c] + EPSV);
      s += w2g[t*NF + c]*(betag[c] - mmg[c]*A);
    }
    g_const[t] = s;
  }

  for (int q = lid; q < NTILE; q += 256) ht[q] = 0;
  __syncthreads();
  for (int i = blockIdx.x*256 + lid; i < NLD; i += 64*256) {
    int cell = idx[i];
    int h = cell >> 9, w = cell & 511;
    int thA = (h-2)>>4, thB = (h+2)>>4;
    int twA = (w-2)>>4, twB = (w+2)>>4;
    #pragma unroll
    for (int ah = 0; ah < 2; ++ah) {
      int th = ah ? thB : thA;
      if (th < 0 || th > 31 || (ah && thB == thA)) continue;
      #pragma unroll
      for (int aw = 0; aw < 2; ++aw) {
        int tw = aw ? twB : twA;
        if (tw < 0 || tw > 31 || (aw && twB == twA)) continue;
        atomicAdd(&ht[th*32 + tw], 1u);
      }
    }
  }
  __syncthreads();
  for (int q = lid; q < NTILE; q += 256) {
    bt[q] = ht[q] ? atomicAdd(&g_tcnt[q], ht[q]) : 0u;
    ht[q] = 0;
  }
  __syncthreads();
  for (int i = blockIdx.x*256 + lid; i < NLD; i += 64*256) {
    int cell = idx[i];
    int h = cell >> 9, w = cell & 511;
    int thA = (h-2)>>4, thB = (h+2)>>4;
    int twA = (w-2)>>4, twB = (w+2)>>4;
    #pragma unroll
    for (int ah = 0; ah < 2; ++ah) {
      int th = ah ? thB : thA;
      if (th < 0 || th > 31 || (ah && thB == thA)) continue;
      #pragma unroll
      for (int aw = 0; aw < 2; ++aw) {
        int tw = aw ? twB : twA;
        if (tw < 0 || tw > 31 || (aw && twB == twA)) continue;
        int t = th*32 + tw;
        unsigned pt = bt[t] + atomicAdd(&ht[t], 1u);
        unsigned pos = (unsigned)(h - th*16 + 2)*20u + (unsigned)(w - tw*16 + 2);
        if (pt < CAPT) g_tbkt[(size_t)t*CAPT + pt] = ((unsigned)i << 9) | pos;
      }
    }
  }
}

// ---- conv: tile x batch-pair. K=16 dual-MFMA: proj's B-fragment layout
// equals conv1's D layout -> conv1 output feeds proj DIRECTLY (no
// cross-lane regroup). All 4 k-groups carry real data. ----
__global__ __launch_bounds__(256, 4) void conv_k(
    const uint2* __restrict__ w1Ag, const uint2* __restrict__ w2Ag,
    const float* __restrict__ g_const, const float* __restrict__ b2g,
    const float* __restrict__ x,
    const unsigned* __restrict__ g_tcnt, const unsigned* __restrict__ g_tbkt,
    float* __restrict__ out)
{
  __shared__ float s_gridf[2*HCELLS];                  // scatter acc; reused as ytile
  __shared__ unsigned s_gE[2][GR*RDW];                 // bf16-pair copies, even start
  __shared__ unsigned s_gO[2][GR*RDW];                 // odd start
  __shared__ __align__(8) unsigned short s_projb[2*PBUF];
  __shared__ float s_const[12];
  // ~19.5 KB

  const int lid = threadIdx.x;
  const int j = blockIdx.x;
  const int b0 = (j & 15) * 2;
  const int tile = j >> 4;
  const int ty0 = (tile >> 5) * TILE, tx0 = (tile & 31) * TILE;

  const int l = lid & 63;
  const int wid = lid >> 6;
  const bf16x4 w1frag = __builtin_bit_cast(bf16x4, w1Ag[l]);
  const bf16x4 w2frag = __builtin_bit_cast(bf16x4, w2Ag[l]);

  if (lid < 9) s_const[lid] = g_const[lid];
  for (int q = lid; q < 2*HCELLS; q += 256) s_gridf[q] = 0.f;
  __syncthreads();

  const unsigned nT = min(g_tcnt[tile], (unsigned)CAPT);
  const unsigned* tb = g_tbkt + (size_t)tile*CAPT;
  const float* xb0 = x + (size_t)b0*NLD;
  const float* xb1 = xb0 + NLD;
  for (unsigned k2 = lid; k2 < nT; k2 += 256) {
    unsigned e = tb[k2];
    unsigned pos = e & 511, i = e >> 9;
    atomicAdd(&s_gridf[pos],          xb0[i]);
    atomicAdd(&s_gridf[HCELLS + pos], xb1[i]);
  }
  __syncthreads();

  // quantize to bf16 pair-copies: E dword jd = cells {2jd,2jd+1}; O = {2jd+1,2jd+2}
  for (int q = lid; q < 2*GR*RDW; q += 256) {
    int bb = q >= GR*RDW;
    int rj = q - bb*GR*RDW;
    int r = rj / RDW, jd = rj - r*RDW;
    const float* f = &s_gridf[bb*HCELLS + r*GR];
    int c0 = jd*2;
    s_gE[bb][rj] = cvtpk(f[c0], f[c0+1]);
    s_gO[bb][rj] = cvtpk(f[c0+1], (c0+2 < GR) ? f[c0+2] : 0.f);
  }
  __syncthreads();

  // ---- A+P: K=16 chain, no cross-lane regroup ----
  {
    const int n_px = l & 15, kg = l >> 4;

    for (int grp = wid; grp < NGRP; grp += 4) {
      int p = grp*16 + n_px;
      unsigned rr = ((unsigned)p * 3641u) >> 16;     // p/18
      unsigned cc = (unsigned)p - rr*18u;
      int yh = ty0 - 1 + (int)rr, yw = tx0 - 1 + (int)cc;
      bool val = ((unsigned)yh < HH) & ((unsigned)yw < WW);
      int o = (int)rr*RDW + (int)(cc >> 1) + kg*RDW;   // kg = window row
      const unsigned* g0 = (cc & 1) ? s_gO[0] : s_gE[0];
      const unsigned* g1 = (cc & 1) ? s_gO[1] : s_gE[1];

      // gfrag: kg0/1/2 = window rows rr..rr+2 (4 cells, col3 junk); kg3 = bias 1.0 @k12
      unsigned ga0, ga1, gb0, gb1;
      if (kg < 3) { ga0 = g0[o]; ga1 = g0[o+1]; gb0 = g1[o]; gb1 = g1[o+1]; }
      else        { ga0 = 0x00003F80u; ga1 = 0u; gb0 = 0x00003F80u; gb1 = 0u; }
      bf16x4 gf0 = __builtin_bit_cast(bf16x4, make_uint2(ga0, ga1));
      bf16x4 gf1 = __builtin_bit_cast(bf16x4, make_uint2(gb0, gb1));

      // conv1+bias x2 (K=16)
      f32x4 z = {0.f,0.f,0.f,0.f};
      f32x4 d10 = mfma16(w1frag, gf0, z);
      f32x4 d11 = mfma16(w1frag, gf1, z);

      // relu + pack; D layout == proj B layout (lane: px=l&15, ch 4kg..4kg+3)
      unsigned u0a = cvtpk(fmaxf(d10[0],0.f), fmaxf(d10[1],0.f));
      unsigned u0b = cvtpk(fmaxf(d10[2],0.f), fmaxf(d10[3],0.f));
      unsigned u1a = cvtpk(fmaxf(d11[0],0.f), fmaxf(d11[1],0.f));
      unsigned u1b = cvtpk(fmaxf(d11[2],0.f), fmaxf(d11[3],0.f));
      if (!val) { u0a = u0b = u1a = u1b = 0u; }        // OOB y1 -> 0
      bf16x4 bf0 = __builtin_bit_cast(bf16x4, make_uint2(u0a, u0b));
      bf16x4 bf1 = __builtin_bit_cast(bf16x4, make_uint2(u1a, u1b));

      // proj x2 (K=16): D rows = taps 4kg..4kg+3
      f32x4 d0 = mfma16(w2frag, bf0, z);
      f32x4 d1 = mfma16(w2frag, bf1, z);

      if (kg < 2) {
        *(uint2*)&s_projb[p*PSTRB + kg*4]        = make_uint2(cvtpk(d0[0],d0[1]), cvtpk(d0[2],d0[3]));
        *(uint2*)&s_projb[PBUF + p*PSTRB + kg*4] = make_uint2(cvtpk(d1[0],d1[1]), cvtpk(d1[2],d1[3]));
      } else if (kg == 2) {
        s_projb[p*PSTRB + 8]        = (unsigned short)(cvtpk(d0[0], d0[0]) & 0xFFFFu);  // tap 8
        s_projb[PBUF + p*PSTRB + 8] = (unsigned short)(cvtpk(d1[0], d1[0]) & 0xFFFFu);
      }
    }
  }
  __syncthreads();

  // ---- phase B: out = b2 + sum_{valid t} const_t + sum_t proj[t] ----
  float* s_ytile = s_gridf;
  {
    const int ty = lid >> 4, tx = lid & 15;
    bool vh[3], vw[3];
    #pragma unroll
    for (int kk = 0; kk < 3; ++kk) {
      vh[kk] = (unsigned)(ty0 + ty + kk - 1) < HH;
      vw[kk] = (unsigned)(tx0 + tx + kk - 1) < WW;
    }
    float base = b2g[0];
    float acc0 = 0.f, acc1 = 0.f;
    #pragma unroll
    for (int kh = 0; kh < 3; ++kh)
      #pragma unroll
      for (int kw = 0; kw < 3; ++kw) {
        if (vh[kh] & vw[kw]) base += s_const[kh*3+kw];
        int o = ((ty+kh)*YR + tx+kw)*PSTRB + kh*3+kw;
        acc0 += __uint_as_float((unsigned)s_projb[o] << 16);
        acc1 += __uint_as_float((unsigned)s_projb[PBUF + o] << 16);
      }
    s_ytile[lid]       = base + acc0;
    s_ytile[256 + lid] = base + acc1;
  }
  __syncthreads();

  // ---- fused gather epilogue ----
  for (unsigned k2 = lid; k2 < nT; k2 += 256) {
    unsigned e = tb[k2];
    unsigned pos = e & 511;
    unsigned py = (pos * 3277u) >> 16;   // pos/20
    unsigned px2 = pos - py*20u;
    if (py >= 2 && py < 18 && px2 >= 2 && px2 < 18) {
      unsigned i = e >> 9;
      int o = (int)((py-2)*16 + (px2-2));
      out[(size_t)b0*NLD + i]     = xb0[i] + s_ytile[o];
      out[(size_t)(b0+1)*NLD + i] = xb1[i] + s_ytile[256 + o];
    }
  }
}

extern "C" void kernel_launch(void* const* d_in, const int* in_sizes, int n_in,
                              void* d_out, int out_size, void* d_ws, size_t ws_size,
                              hipStream_t stream) {
  const float* x     = (const float*)d_in[0];
  const float* w1    = (const float*)d_in[1];
  const float* b1    = (const float*)d_in[2];
  const float* gamma = (const float*)d_in[3];
  const float* beta  = (const float*)d_in[4];
  const float* mmean = (const float*)d_in[5];
  const float* mvar  = (const float*)d_in[6];
  const float* w2    = (const float*)d_in[7];
  const float* b2    = (const float*)d_in[8];
  const int*   idx   = (const int*)d_in[9];
  float* out = (float*)d_out;

  unsigned* g_tcnt = (unsigned*)d_ws;                     // 1024
  unsigned* g_tbkt = g_tcnt + NTILE;                      // 1 MB
  uint2*    w1A    = (uint2*)(g_tbkt + (size_t)NTILE*CAPT);
  uint2*    w2A    = w1A + 64;
  float*    gconst = (float*)(w2A + 64);                  // 9 floats

  (void)hipMemsetAsync(g_tcnt, 0, NTILE*sizeof(unsigned), stream);

  bin_k<<<dim3(64), dim3(256), 0, stream>>>(idx, w1, b1, w2, gamma, beta,
                                            mmean, mvar, w1A, w2A, gconst,
                                            g_tcnt, g_tbkt);

  conv_k<<<dim3((NB/2) * NTILE), dim3(256), 0, stream>>>(
      w1A, w2A, gconst, b2, x, g_tcnt, g_tbkt, out);
}